// Round 1
// baseline (358.940 us; speedup 1.0000x reference)
//
#include <hip/hip_runtime.h>
#include <hip/hip_bf16.h>

// Fused self-attention for B=32, H=W=64, C=256.
// One block per (b, 16-channel group): 512 blocks x 1024 threads (16 waves).
// All four 64x64x64 matmuls per channel use v_mfma_f32_16x16x32_bf16.
//
// LDS map (150784 B of 163840):
//   Xs  : 16 slots x 8208 B  bf16 X[h][w] (XOR-swizzled 16B chunks) -> becomes out[h][m] per slot
//   R1  : 9216 B (rows 144 B) WqT[k][w] -> q[h][k] -> Tb[m][w] (normalized S^T, bf16)
//   R2  : 9216 B (rows 144 B) WkT[k][w] -> K[m][k]
//   part: 4x64 f32 softmax column partial sums

typedef short short8 __attribute__((ext_vector_type(8)));   // 8 bf16 (4 VGPRs)
typedef float floatx4 __attribute__((ext_vector_type(4)));  // MFMA acc

#define SLOT 8208          // 64*128 data + 16 pad (bank-spreads slot bases)
#define R1_OFF (16*SLOT)   // 131328
#define R2_OFF (R1_OFF + 9216)
#define PART_OFF (R2_OFF + 9216)
#define LDS_BYTES (PART_OFF + 4*64*4)

__device__ __forceinline__ unsigned short f2bf(float f) {
  unsigned u = __float_as_uint(f);
  unsigned r = (u + 0x7FFFu + ((u >> 16) & 1u)) >> 16;   // RNE
  return (unsigned short)r;
}

__global__ __launch_bounds__(1024) void fused_attn(
    const float* __restrict__ x, const float* __restrict__ Wq,
    const float* __restrict__ Wk, float* __restrict__ out) {
  __shared__ __align__(16) unsigned char smem[LDS_BYTES];

  const int tid  = threadIdx.x;
  const int b    = blockIdx.x >> 4;
  const int c0   = (blockIdx.x & 15) << 4;
  const int lane = tid & 63;
  const int wid  = tid >> 6;
  const int l15  = lane & 15;
  const int quad = lane >> 4;
  const int rt   = wid >> 2;   // row-tile of this wave
  const int ct   = wid & 3;    // col-tile of this wave

  unsigned char* Xs = smem;
  unsigned char* R1 = smem + R1_OFF;
  unsigned char* R2 = smem + R2_OFF;
  float* part = (float*)(smem + PART_OFF);

  // ---------------- Phase A: stage X for all 16 channels (full-line reads) ---
  {
    const int c4 = tid & 3;            // which float4 of the 16-c group
    const int hwb = tid >> 2;          // 0..255
    const float* xb = x + (size_t)b * 4096 * 256 + c0 + c4 * 4;
    for (int it = 0; it < 16; ++it) {
      int hw = hwb + it * 256;
      int h = hw >> 6, w = hw & 63;
      float4 v = *(const float4*)(xb + (size_t)hw * 256);
      float vv[4] = {v.x, v.y, v.z, v.w};
      int chunk = (w >> 3) ^ (h & 7);                      // XOR swizzle
      int off = (h << 7) + (chunk << 4) + ((w & 7) << 1);
#pragma unroll
      for (int j = 0; j < 4; ++j)
        *(unsigned short*)(Xs + (c4 * 4 + j) * SLOT + off) = f2bf(vv[j]);
    }
  }
  __syncthreads();

  const floatx4 zero4 = {0.f, 0.f, 0.f, 0.f};

  // ---------------- Phase B: per-channel chain --------------------------------
  for (int ci = 0; ci < 16; ++ci) {
    const int c = c0 + ci;

    // B1: stage WqT -> R1, WkT -> R2 (transposed: rows = k_out, cols = w)
    {
      const int k  = tid & 63;     // k_out (contiguous in global -> coalesced)
      const int w0 = tid >> 6;     // 0..15
      const float* wqp = Wq + (size_t)c * 4096 + k;
      const float* wkp = Wk + (size_t)c * 4096 + k;
#pragma unroll
      for (int p = 0; p < 4; ++p) {
        int w = w0 + p * 16;
        *(unsigned short*)(R1 + k * 144 + w * 2) = f2bf(wqp[(size_t)w * 64]);
        *(unsigned short*)(R2 + k * 144 + w * 2) = f2bf(wkp[(size_t)w * 64]);
      }
    }
    __syncthreads();  // W staged

    // B2: q = hs(X@Wq), K = tanh(X@Wk)  (tile (rt,ct) per wave)
    floatx4 accq = zero4, acck = zero4;
#pragma unroll
    for (int ks = 0; ks < 2; ++ks) {
      int r = rt * 16 + l15;
      int chunk = (ks * 4 + quad) ^ (r & 7);
      short8 a = *(const short8*)(Xs + ci * SLOT + r * 128 + chunk * 16);
      int n = ct * 16 + l15;
      short8 bq = *(const short8*)(R1 + n * 144 + ks * 64 + quad * 16);
      short8 bk = *(const short8*)(R2 + n * 144 + ks * 64 + quad * 16);
      accq = __builtin_amdgcn_mfma_f32_16x16x32_bf16(a, bq, accq, 0, 0, 0);
      acck = __builtin_amdgcn_mfma_f32_16x16x32_bf16(a, bk, acck, 0, 0, 0);
    }
    unsigned short qb[4], kb[4];
#pragma unroll
    for (int i = 0; i < 4; ++i) {
      float qv = fminf(fmaxf(0.2f * accq[i] + 0.5f, 0.f), 1.f);
      float t  = __expf(2.f * acck[i]);
      float kv = 1.f - 2.f / (t + 1.f);                    // tanh
      qb[i] = f2bf(qv);
      kb[i] = f2bf(kv);
    }
    __syncthreads();  // everyone done reading W before overwrite

    // B3: q over R1 (rows h), K over R2 (rows m)
    {
      int kcol = ct * 16 + l15;
#pragma unroll
      for (int i = 0; i < 4; ++i) {
        int h = rt * 16 + quad * 4 + i;
        *(unsigned short*)(R1 + h * 144 + kcol * 2) = qb[i];
        *(unsigned short*)(R2 + h * 144 + kcol * 2) = kb[i];
      }
    }
    __syncthreads();

    // B4: S^T = K . q^T (rows mm = softmax axis, cols rr)
    floatx4 accs = zero4;
#pragma unroll
    for (int ks = 0; ks < 2; ++ks) {
      int mm = rt * 16 + l15;
      short8 a  = *(const short8*)(R2 + mm * 144 + ks * 64 + quad * 16);
      int rr = ct * 16 + l15;
      short8 bb = *(const short8*)(R1 + rr * 144 + ks * 64 + quad * 16);
      accs = __builtin_amdgcn_mfma_f32_16x16x32_bf16(a, bb, accs, 0, 0, 0);
    }
    float e[4];
    float psum = 0.f;
#pragma unroll
    for (int i = 0; i < 4; ++i) {
      float s = fminf(fmaxf(0.2f * accs[i] + 0.5f, 0.f), 1.f);  // hs in [0,1]:
      e[i] = __expf(s);                                          // no max-sub needed
      psum += e[i];
    }
    psum += __shfl_xor(psum, 16, 64);   // reduce across quads (column pieces)
    psum += __shfl_xor(psum, 32, 64);
    if (quad == 0) part[rt * 64 + ct * 16 + l15] = psum;
    __syncthreads();  // q reads done + partials visible

    // B5: normalize in regs, write Tb = S^T (bf16) over R1
    {
      int rr = ct * 16 + l15;
      float s = part[rr] + part[64 + rr] + part[128 + rr] + part[192 + rr];
      float inv = 1.f / s;
#pragma unroll
      for (int i = 0; i < 4; ++i) {
        int mm = rt * 16 + quad * 4 + i;
        *(unsigned short*)(R1 + mm * 144 + rr * 2) = f2bf(e[i] * inv);
      }
    }
    __syncthreads();

    // B6: out = X . S   (B-operand = Tb rows n=m, contiguous w)
    floatx4 acco = zero4;
#pragma unroll
    for (int ks = 0; ks < 2; ++ks) {
      int r = rt * 16 + l15;
      int chunk = (ks * 4 + quad) ^ (r & 7);
      short8 a  = *(const short8*)(Xs + ci * SLOT + r * 128 + chunk * 16);
      int n = ct * 16 + l15;
      short8 bb = *(const short8*)(R1 + n * 144 + ks * 64 + quad * 16);
      acco = __builtin_amdgcn_mfma_f32_16x16x32_bf16(a, bb, acco, 0, 0, 0);
    }
    __syncthreads();  // X slot ci reads done before overwrite

    // B7: stage out tile into slot ci (plain layout h*128 + m*2)
    {
      int m = ct * 16 + l15;
#pragma unroll
      for (int i = 0; i < 4; ++i) {
        int h = rt * 16 + quad * 4 + i;
        *(unsigned short*)(Xs + ci * SLOT + h * 128 + m * 2) = f2bf(acco[i]);
      }
    }
    // next-iter barrier (after B1) orders B7 vs later readers; regions disjoint
  }
  __syncthreads();

  // ---------------- Phase C: coalesced output (64 B full line per thread) -----
  for (int rep = 0; rep < 4; ++rep) {
    int hm = tid + rep * 1024;           // (h,m) linear
    int loff = (hm >> 6) * 128 + (hm & 63) * 2;
    float vals[16];
#pragma unroll
    for (int s = 0; s < 16; ++s) {
      unsigned short us = *(const unsigned short*)(Xs + s * SLOT + loff);
      vals[s] = __uint_as_float(((unsigned)us) << 16);
    }
    float* op = out + ((size_t)b * 4096 + hm) * 256 + c0;
#pragma unroll
    for (int g = 0; g < 4; ++g) {
      float4 v = {vals[4 * g], vals[4 * g + 1], vals[4 * g + 2], vals[4 * g + 3]};
      *(float4*)(op + 4 * g) = v;
    }
  }
}

extern "C" void kernel_launch(void* const* d_in, const int* in_sizes, int n_in,
                              void* d_out, int out_size, void* d_ws, size_t ws_size,
                              hipStream_t stream) {
  const float* x  = (const float*)d_in[0];
  const float* Wq = (const float*)d_in[1];
  const float* Wk = (const float*)d_in[2];
  float* o = (float*)d_out;
  fused_attn<<<dim3(512), dim3(1024), 0, stream>>>(x, Wq, Wk, o);
}

// Round 2
// 325.416 us; speedup vs baseline: 1.1030x; 1.1030x over previous
//
#include <hip/hip_runtime.h>
#include <hip/hip_bf16.h>

// Fused self-attention, B=32, H=W=64, C=256.
// One WAVE per (b,c) chain: zero inner barriers. Block = 4 waves = 4 channels.
// Grid = 2048 (cg-major: 32 consecutive blocks share W[c] slice for L2 reuse).
//
// Per-wave LDS (16896 B): buf0 (8192): X staged -> q[w'][k] -> SnT[m][w']
//                         buf1 (8704): WqS/WkS [w][k] (stride 136) -> K[m][k] -> out[h][m]
// All matrix LDS buffers: 64 rows x 128 B bf16, XOR-swizzled 16B chunks
// (chunk = (col>>3) ^ (row&7)) -> b64 writes / b128 reads, <=2-way conflicts (free).
//
// Orientation trick: compute qT=(WqT)(X), KT=(WkT)(X), S=(q)(K), outT=(SnT)(X)
// so every MFMA C-layout lane holds 4 CONTIGUOUS elements of the next LDS row.

typedef short short8 __attribute__((ext_vector_type(8)));
typedef float floatx4 __attribute__((ext_vector_type(4)));
typedef unsigned int uint;

#define PW 16896
#define BUF1_OFF 8192

__device__ __forceinline__ uint bfr(float f) {          // f32 -> bf16 (RNE)
  uint u = __float_as_uint(f);
  return (u + 0x7FFFu + ((u >> 16) & 1u)) >> 16;
}
__device__ __forceinline__ uint pk2(float a, float b) { // pack 2 bf16
  return bfr(a) | (bfr(b) << 16);
}
__device__ __forceinline__ short8 u4s8(uint a, uint b, uint c, uint d) {
  union { uint u[4]; short8 s; } t;
  t.u[0] = a; t.u[1] = b; t.u[2] = c; t.u[3] = d;
  return t.s;
}
__device__ __forceinline__ float hsg(float x) {
  return fminf(fmaxf(0.2f * x + 0.5f, 0.f), 1.f);
}

__global__ __launch_bounds__(256, 2) void fused_attn(
    const float* __restrict__ x, const float* __restrict__ Wq,
    const float* __restrict__ Wk, float* __restrict__ out) {
  __shared__ __align__(16) unsigned char smem[4 * PW];

  const int tid  = threadIdx.x;
  const int lane = tid & 63;
  const int wid  = tid >> 6;
  const int l15  = lane & 15;
  const int quad = lane >> 4;

  const int b  = blockIdx.x & 31;        // b inner: consecutive blocks share W[c]
  const int cg = blockIdx.x >> 5;
  const int c0 = cg << 2;
  const int c  = c0 + wid;

  unsigned char* buf0 = smem + wid * PW;
  unsigned char* buf1 = buf0 + BUF1_OFF;

  // ---- Phase A: cooperative X staging (4 channels, float4 = 16B/lane) ------
  {
    const float* xb = x + (size_t)b * 4096 * 256 + c0;
#pragma unroll 4
    for (int it = 0; it < 16; ++it) {
      int hw = it * 256 + tid;                    // per wave: h fixed, w = lane
      float4 v = *(const float4*)(xb + (size_t)hw * 256);
      int h = hw >> 6, w = hw & 63;
      uint off = (uint)(h * 128 + (((w >> 3) ^ (h & 7)) << 4) + ((w & 7) << 1));
      float vv[4] = {v.x, v.y, v.z, v.w};
#pragma unroll
      for (int j = 0; j < 4; ++j)
        *(unsigned short*)(smem + j * PW + off) = (unsigned short)bfr(vv[j]);
    }
  }
  __syncthreads();

  // ---- X fragments -> registers (A/B-operand layout), buf0 becomes free ----
  short8 xf[4][2];
#pragma unroll
  for (int rt = 0; rt < 4; ++rt) {
    int r = rt * 16 + l15;
#pragma unroll
    for (int ks = 0; ks < 2; ++ks)
      xf[rt][ks] = *(const short8*)(buf0 + r * 128 + ((((ks * 4 + quad) ^ (r & 7))) << 4));
  }

  const floatx4 zero4 = {0.f, 0.f, 0.f, 0.f};
  floatx4 acc[16];

  // ==== M1: qT = WqT x X  ->  q[w'][k] into buf0 (hard_sigmoid applied) =====
  {
    const float* wp = Wq + (size_t)c * 4096;
#pragma unroll 4
    for (int j = 0; j < 16; ++j) {                // stage WqS[w][k], stride 136
      int f4 = j * 64 + lane;
      float4 v = *(const float4*)(wp + (size_t)f4 * 4);
      int w = f4 >> 4, k0 = (f4 & 15) << 2;
      uint2 pk; pk.x = pk2(v.x, v.y); pk.y = pk2(v.z, v.w);
      *(uint2*)(buf1 + w * 136 + k0 * 2) = pk;
    }
  }
#pragma unroll
  for (int i = 0; i < 16; ++i) acc[i] = zero4;
#pragma unroll
  for (int kt = 0; kt < 4; ++kt) {
    short8 af[2];
#pragma unroll
    for (int ks = 0; ks < 2; ++ks) {              // transposed u16 gather (2-way, free)
      const unsigned short* p = (const unsigned short*)buf1 + (ks * 32 + quad * 8) * 68 + (kt * 16 + l15);
      af[ks] = u4s8((uint)p[0]   | ((uint)p[68]  << 16),
                    (uint)p[136] | ((uint)p[204] << 16),
                    (uint)p[272] | ((uint)p[340] << 16),
                    (uint)p[408] | ((uint)p[476] << 16));
    }
#pragma unroll
    for (int ht = 0; ht < 4; ++ht) {
      acc[kt * 4 + ht] = __builtin_amdgcn_mfma_f32_16x16x32_bf16(af[0], xf[ht][0], acc[kt * 4 + ht], 0, 0, 0);
      acc[kt * 4 + ht] = __builtin_amdgcn_mfma_f32_16x16x32_bf16(af[1], xf[ht][1], acc[kt * 4 + ht], 0, 0, 0);
    }
  }
#pragma unroll
  for (int kt = 0; kt < 4; ++kt)
#pragma unroll
    for (int ht = 0; ht < 4; ++ht) {              // lane: fixed h, 4 consecutive k -> b64
      floatx4 a = acc[kt * 4 + ht];
      uint2 pk; pk.x = pk2(hsg(a[0]), hsg(a[1])); pk.y = pk2(hsg(a[2]), hsg(a[3]));
      int h = ht * 16 + l15;
      *(uint2*)(buf0 + h * 128 + ((((kt * 2 + (quad >> 1)) ^ (h & 7))) << 4) + ((quad & 1) << 3)) = pk;
    }

  // ==== M2: KT = WkT x X  ->  K[m][k] into buf1 (tanh applied) ==============
  {
    const float* wp = Wk + (size_t)c * 4096;
#pragma unroll 4
    for (int j = 0; j < 16; ++j) {
      int f4 = j * 64 + lane;
      float4 v = *(const float4*)(wp + (size_t)f4 * 4);
      int w = f4 >> 4, k0 = (f4 & 15) << 2;
      uint2 pk; pk.x = pk2(v.x, v.y); pk.y = pk2(v.z, v.w);
      *(uint2*)(buf1 + w * 136 + k0 * 2) = pk;
    }
  }
#pragma unroll
  for (int i = 0; i < 16; ++i) acc[i] = zero4;
#pragma unroll
  for (int kt = 0; kt < 4; ++kt) {
    short8 af[2];
#pragma unroll
    for (int ks = 0; ks < 2; ++ks) {
      const unsigned short* p = (const unsigned short*)buf1 + (ks * 32 + quad * 8) * 68 + (kt * 16 + l15);
      af[ks] = u4s8((uint)p[0]   | ((uint)p[68]  << 16),
                    (uint)p[136] | ((uint)p[204] << 16),
                    (uint)p[272] | ((uint)p[340] << 16),
                    (uint)p[408] | ((uint)p[476] << 16));
    }
#pragma unroll
    for (int ht = 0; ht < 4; ++ht) {
      acc[kt * 4 + ht] = __builtin_amdgcn_mfma_f32_16x16x32_bf16(af[0], xf[ht][0], acc[kt * 4 + ht], 0, 0, 0);
      acc[kt * 4 + ht] = __builtin_amdgcn_mfma_f32_16x16x32_bf16(af[1], xf[ht][1], acc[kt * 4 + ht], 0, 0, 0);
    }
  }
#pragma unroll
  for (int kt = 0; kt < 4; ++kt)
#pragma unroll
    for (int ht = 0; ht < 4; ++ht) {              // K overwrites WkS (fully consumed)
      floatx4 a = acc[kt * 4 + ht];
      float kv[4];
#pragma unroll
      for (int i = 0; i < 4; ++i) {
        float t = __expf(2.f * a[i]);
        kv[i] = 1.f - 2.f / (t + 1.f);            // tanh
      }
      uint2 pk; pk.x = pk2(kv[0], kv[1]); pk.y = pk2(kv[2], kv[3]);
      int m = ht * 16 + l15;
      *(uint2*)(buf1 + m * 128 + ((((kt * 2 + (quad >> 1)) ^ (m & 7))) << 4) + ((quad & 1) << 3)) = pk;
    }

  // ==== M3: S = q x K^T, softmax over m, SnT[m][w'] into buf0 ===============
  short8 kf[4][2];
#pragma unroll
  for (int mt = 0; mt < 4; ++mt) {
    int r = mt * 16 + l15;
#pragma unroll
    for (int ks = 0; ks < 2; ++ks)
      kf[mt][ks] = *(const short8*)(buf1 + r * 128 + ((((ks * 4 + quad) ^ (r & 7))) << 4));
  }
#pragma unroll
  for (int i = 0; i < 16; ++i) acc[i] = zero4;
#pragma unroll
  for (int wt = 0; wt < 4; ++wt) {
    int r = wt * 16 + l15;
    short8 qf0 = *(const short8*)(buf0 + r * 128 + (((quad ^ (r & 7))) << 4));
    short8 qf1 = *(const short8*)(buf0 + r * 128 + ((((4 + quad) ^ (r & 7))) << 4));
#pragma unroll
    for (int mt = 0; mt < 4; ++mt) {
      acc[wt * 4 + mt] = __builtin_amdgcn_mfma_f32_16x16x32_bf16(qf0, kf[mt][0], acc[wt * 4 + mt], 0, 0, 0);
      acc[wt * 4 + mt] = __builtin_amdgcn_mfma_f32_16x16x32_bf16(qf1, kf[mt][1], acc[wt * 4 + mt], 0, 0, 0);
    }
  }
  // e = exp(hs(s)); hs in [0,1] -> no max subtraction needed
#pragma unroll
  for (int i = 0; i < 16; ++i)
#pragma unroll
    for (int j = 0; j < 4; ++j) acc[i][j] = __expf(hsg(acc[i][j]));
  float inv[4][4];
#pragma unroll
  for (int wt = 0; wt < 4; ++wt)
#pragma unroll
    for (int i = 0; i < 4; ++i) {                 // row sum: 3 adds + 4 shfls (16-lane)
      float p = acc[wt * 4 + 0][i] + acc[wt * 4 + 1][i] + acc[wt * 4 + 2][i] + acc[wt * 4 + 3][i];
      p += __shfl_xor(p, 1, 16);
      p += __shfl_xor(p, 2, 16);
      p += __shfl_xor(p, 4, 16);
      p += __shfl_xor(p, 8, 16);
      inv[wt][i] = 1.f / p;
    }
#pragma unroll
  for (int wt = 0; wt < 4; ++wt)
#pragma unroll
    for (int mt = 0; mt < 4; ++mt) {              // lane: fixed m, 4 consecutive w' -> b64
      floatx4 a = acc[wt * 4 + mt];
      uint2 pk;
      pk.x = pk2(a[0] * inv[wt][0], a[1] * inv[wt][1]);
      pk.y = pk2(a[2] * inv[wt][2], a[3] * inv[wt][3]);
      int m = mt * 16 + l15;
      *(uint2*)(buf0 + m * 128 + ((((wt * 2 + (quad >> 1)) ^ (m & 7))) << 4) + ((quad & 1) << 3)) = pk;
    }

  // ==== M4: outT = SnT x X  ->  out[h][m] into buf1 =========================
#pragma unroll
  for (int i = 0; i < 16; ++i) acc[i] = zero4;
#pragma unroll
  for (int mt = 0; mt < 4; ++mt) {
    int r = mt * 16 + l15;
    short8 sf0 = *(const short8*)(buf0 + r * 128 + (((quad ^ (r & 7))) << 4));
    short8 sf1 = *(const short8*)(buf0 + r * 128 + ((((4 + quad) ^ (r & 7))) << 4));
#pragma unroll
    for (int ht = 0; ht < 4; ++ht) {
      acc[mt * 4 + ht] = __builtin_amdgcn_mfma_f32_16x16x32_bf16(sf0, xf[ht][0], acc[mt * 4 + ht], 0, 0, 0);
      acc[mt * 4 + ht] = __builtin_amdgcn_mfma_f32_16x16x32_bf16(sf1, xf[ht][1], acc[mt * 4 + ht], 0, 0, 0);
    }
  }
#pragma unroll
  for (int mt = 0; mt < 4; ++mt)
#pragma unroll
    for (int ht = 0; ht < 4; ++ht) {              // lane: fixed h, 4 consecutive m -> b64
      floatx4 a = acc[mt * 4 + ht];
      uint2 pk; pk.x = pk2(a[0], a[1]); pk.y = pk2(a[2], a[3]);
      int h = ht * 16 + l15;
      *(uint2*)(buf1 + h * 128 + ((((mt * 2 + (quad >> 1)) ^ (h & 7))) << 4) + ((quad & 1) << 3)) = pk;
    }
  __syncthreads();

  // ---- Phase C: cooperative output (b64 slot reads, float4 global stores) --
  const size_t outbase = (size_t)b * 4096 * 256 + c0;
#pragma unroll
  for (int rep = 0; rep < 4; ++rep) {
    int idx = rep * 256 + tid;
    int h = idx >> 4, mq = idx & 15;              // m0 = mq*4
    uint loff = (uint)(h * 128 + ((((mq >> 1) ^ (h & 7))) << 4) + ((mq & 1) << 3));
    float vals[4][4];
#pragma unroll
    for (int j = 0; j < 4; ++j) {
      uint2 d = *(const uint2*)(smem + j * PW + BUF1_OFF + loff);
      vals[j][0] = __uint_as_float(d.x << 16);
      vals[j][1] = __uint_as_float(d.x & 0xFFFF0000u);
      vals[j][2] = __uint_as_float(d.y << 16);
      vals[j][3] = __uint_as_float(d.y & 0xFFFF0000u);
    }
    float* op = out + outbase + (size_t)(h * 64 + mq * 4) * 256;
#pragma unroll
    for (int jj = 0; jj < 4; ++jj) {
      float4 v = {vals[0][jj], vals[1][jj], vals[2][jj], vals[3][jj]};
      *(float4*)(op + (size_t)jj * 256) = v;
    }
  }
}

extern "C" void kernel_launch(void* const* d_in, const int* in_sizes, int n_in,
                              void* d_out, int out_size, void* d_ws, size_t ws_size,
                              hipStream_t stream) {
  const float* x  = (const float*)d_in[0];
  const float* Wq = (const float*)d_in[1];
  const float* Wk = (const float*)d_in[2];
  float* o = (float*)d_out;
  fused_attn<<<dim3(2048), dim3(256), 0, stream>>>(x, Wq, Wk, o);
}